// Round 4
// baseline (375.988 us; speedup 1.0000x reference)
//
#include <hip/hip_runtime.h>

// ---------------------------------------------------------------------------
// GIN forward. R4: L2-resident sliced gather. Feature tables stored
// slice-major [slice][node][32ch] (3.2MB/slice < 4MB L2/XCD); gather grid
// swizzled so slice = blockIdx % NSLICE lands each slice on one XCD's L2.
// srcs/offs/self/out use nontemporal accesses to avoid evicting the slice.
// CSR build: hist + 2-phase parallel scan + scatter. GEMMs: bf16 MFMA,
// 128x128 tile, BK=32, global_load_lds staging; GEMM2 writes slice-major.
// ---------------------------------------------------------------------------

typedef __attribute__((ext_vector_type(8))) short bf16x8;
typedef __attribute__((ext_vector_type(4))) float f32x4;
typedef __attribute__((ext_vector_type(2))) float f32x2;
typedef __attribute__((ext_vector_type(2))) unsigned short u16x2;

__device__ __forceinline__ float bf2f(unsigned short u) {
  unsigned v = ((unsigned)u) << 16;
  return __builtin_bit_cast(float, v);
}
__device__ __forceinline__ unsigned short f2bf(float f) {
  unsigned u = __builtin_bit_cast(unsigned, f);
  u += 0x7fffu + ((u >> 16) & 1u);
  return (unsigned short)(u >> 16);
}

__device__ __forceinline__ void async16(const void* g, void* l) {
  __builtin_amdgcn_global_load_lds(
      (const __attribute__((address_space(1))) void*)g,
      (__attribute__((address_space(3))) void*)l, 16, 0, 0);
}

static const int NN = 50000;
static const int NE = 800000;
static const int SCAN_NB = 49;             // ceil(50000/1024)
static const int NB16 = NN / 16;           // 3125 node-blocks of 16

// --- x fp32 [NN][128] -> bf16 slice-major [4][NN][32] ----------------------
__global__ __launch_bounds__(256) void k_cvt_sl(const float* __restrict__ x,
    unsigned short* __restrict__ xbS)
{
  int idx = blockIdx.x * 256 + threadIdx.x;      // over NN*64 channel-pairs
  if (idx >= NN * 64) return;
  int node = idx >> 6, cp = idx & 63;
  int ch = cp * 2;
  int s = ch >> 5, co = ch & 31;
  f32x2 v = *reinterpret_cast<const f32x2*>(x + (size_t)node * 128 + ch);
  u16x2 o; o.x = f2bf(v.x); o.y = f2bf(v.y);
  *reinterpret_cast<u16x2*>(xbS + ((size_t)s * NN + node) * 32 + co) = o;
}

// --- all four weights: W [K][N] fp32 -> WT [N][K] bf16, one launch ---------
__global__ __launch_bounds__(256) void k_wcvt_all(
    const float* __restrict__ W1a, const float* __restrict__ W1b,
    const float* __restrict__ W2,  const float* __restrict__ W3,
    unsigned short* __restrict__ WT)
{
  int idx = blockIdx.x * 256 + threadIdx.x;   // 0 .. 196607
  const float* W; unsigned short* out; int K, N, li;
  if (idx < 32768)        { W = W1a; out = WT;          K = 128; N = 256; li = idx; }
  else if (idx < 98304)   { W = W1b; out = WT + 32768;  K = 256; N = 256; li = idx - 32768; }
  else if (idx < 163840)  { W = W2;  out = WT + 98304;  K = 256; N = 256; li = idx - 98304; }
  else if (idx < 196608)  { W = W3;  out = WT + 163840; K = 256; N = 128; li = idx - 163840; }
  else return;
  int n = li / K, k = li - n * K;
  out[li] = f2bf(W[k * N + n]);
}

// --- CSR build: histogram over dst ----------------------------------------
__global__ __launch_bounds__(256) void k_hist(const int* __restrict__ ei,
    int* __restrict__ counts)
{
  int e = blockIdx.x * 256 + threadIdx.x;
  if (e >= NE) return;
  atomicAdd(&counts[ei[NE + e]], 1);
}

// --- scan phase A: per-block inclusive scan (Hillis-Steele in LDS) ---------
__global__ __launch_bounds__(1024) void k_scan_a(const int* __restrict__ counts,
    int* __restrict__ offs, int* __restrict__ bsum)
{
  __shared__ int sh[1024];
  const int t = threadIdx.x;
  int idx = blockIdx.x * 1024 + t;
  int c = (idx < NN) ? counts[idx] : 0;
  sh[t] = c;
  __syncthreads();
  int v = c;
  for (int off = 1; off < 1024; off <<= 1) {
    int tmp = (t >= off) ? sh[t - off] : 0;
    __syncthreads();
    v += tmp; sh[t] = v;
    __syncthreads();
  }
  if (idx < NN) offs[idx] = v - c;
  if (t == 1023) bsum[blockIdx.x] = v;
}

// --- scan phase B: add block bases; copy to cursor; offs[NN]=NE ------------
__global__ __launch_bounds__(1024) void k_scan_b(const int* __restrict__ bsum,
    int* __restrict__ offs, int* __restrict__ cursor)
{
  __shared__ int sb[64];
  const int t = threadIdx.x;
  if (t < SCAN_NB) sb[t] = bsum[t];
  __syncthreads();
  int base = 0;
  for (int j = 0; j < SCAN_NB; j++) base += (j < (int)blockIdx.x) ? sb[j] : 0;
  int idx = blockIdx.x * 1024 + t;
  if (idx < NN) { int o = offs[idx] + base; offs[idx] = o; cursor[idx] = o; }
  if (blockIdx.x == 0 && t == 0) offs[NN] = NE;
}

// --- scatter src ids into CSR order ---------------------------------------
__global__ __launch_bounds__(256) void k_scatter(const int* __restrict__ ei,
    int* __restrict__ cursor, int* __restrict__ srcs)
{
  int e = blockIdx.x * 256 + threadIdx.x;
  if (e >= NE) return;
  int dst = ei[NE + e];
  int pos = atomicAdd(&cursor[dst], 1);
  srcs[pos] = ei[e];
}

// --- sliced gather-aggregate ----------------------------------------------
// featS: bf16 slice-major [NSLICE][NN][32]. out: bf16 row-major [NN][C].
// slice = blockIdx % NSLICE -> XCD round-robin pins slice to one L2.
// 16 lanes per (node, slice), 2 channels per lane, fp32 accumulation.
// L1: self = (1+eps) * x_fp32[node][C]; else self = featS own row.
template<int C, int NSLICE, bool L1>
__global__ __launch_bounds__(256) void k_gather_sl(
    const int* __restrict__ offs, const int* __restrict__ srcs,
    const unsigned short* __restrict__ featS,
    const float* __restrict__ selfx, const float* __restrict__ eps,
    unsigned short* __restrict__ out)
{
  const int s  = blockIdx.x % NSLICE;
  const int nb = blockIdx.x / NSLICE;
  const int g  = threadIdx.x >> 4;
  const int l  = threadIdx.x & 15;
  const int node = nb * 16 + g;
  const int c0 = l * 2;

  const unsigned short* tbl = featS + (size_t)s * NN * 32;

  float a0, a1;
  if (L1) {
    float sc = 1.0f + eps[0];
    f32x2 v = __builtin_nontemporal_load(
        reinterpret_cast<const f32x2*>(selfx + (size_t)node * C + s * 32 + c0));
    a0 = v.x * sc; a1 = v.y * sc;
  } else {
    u16x2 v = *reinterpret_cast<const u16x2*>(tbl + (size_t)node * 32 + c0);
    a0 = bf2f(v.x); a1 = bf2f(v.y);
  }

  int beg = __builtin_nontemporal_load(offs + node);
  int end = __builtin_nontemporal_load(offs + node + 1);
  int i = beg;
  for (; i + 4 <= end; i += 4) {
    int s0 = __builtin_nontemporal_load(srcs + i);
    int s1 = __builtin_nontemporal_load(srcs + i + 1);
    int s2 = __builtin_nontemporal_load(srcs + i + 2);
    int s3 = __builtin_nontemporal_load(srcs + i + 3);
    u16x2 v0 = *reinterpret_cast<const u16x2*>(tbl + (size_t)s0 * 32 + c0);
    u16x2 v1 = *reinterpret_cast<const u16x2*>(tbl + (size_t)s1 * 32 + c0);
    u16x2 v2 = *reinterpret_cast<const u16x2*>(tbl + (size_t)s2 * 32 + c0);
    u16x2 v3 = *reinterpret_cast<const u16x2*>(tbl + (size_t)s3 * 32 + c0);
    a0 += bf2f(v0.x); a1 += bf2f(v0.y);
    a0 += bf2f(v1.x); a1 += bf2f(v1.y);
    a0 += bf2f(v2.x); a1 += bf2f(v2.y);
    a0 += bf2f(v3.x); a1 += bf2f(v3.y);
  }
  for (; i < end; ++i) {
    int s0 = __builtin_nontemporal_load(srcs + i);
    u16x2 v0 = *reinterpret_cast<const u16x2*>(tbl + (size_t)s0 * 32 + c0);
    a0 += bf2f(v0.x); a1 += bf2f(v0.y);
  }

  u16x2 o; o.x = f2bf(a0); o.y = f2bf(a1);
  __builtin_nontemporal_store(o,
      reinterpret_cast<u16x2*>(out + (size_t)node * C + s * 32 + c0));
}

// --- bf16 MFMA GEMM: C = A[M][K] * BT[N][K]^T + bias, optional relu --------
// MODE 0: bf16 row-major out; 2: fp32 row-major out; 3: bf16 slice-major out
template<bool RELU, int MODE>
__global__ __launch_bounds__(256) void k_gemm(
    const unsigned short* __restrict__ A,
    const unsigned short* __restrict__ BT,
    const float* __restrict__ bias,
    unsigned short* __restrict__ Cb,
    float* __restrict__ Cf,
    int M, int K, int N)
{
  __shared__ unsigned short Asb[128 * 32];
  __shared__ unsigned short Bsb[128 * 32];
  const int tid = threadIdx.x;
  const int w = tid >> 6, l = tid & 63;
  const int bm = blockIdx.x * 128, bn = blockIdx.y * 128;
  const int wr = w >> 1, wc = w & 1;

  f32x4 acc[4][4];
#pragma unroll
  for (int m = 0; m < 4; m++)
#pragma unroll
    for (int n = 0; n < 4; n++) acc[m][n] = (f32x4)(0.0f);

  const int lr = l >> 2;
  const int lc = (l & 3) * 8;

  for (int kt = 0; kt < K; kt += 32) {
    __syncthreads();
#pragma unroll
    for (int i = 0; i < 2; i++) {
      int tr = w * 32 + i * 16;
      int ar = bm + tr + lr; if (ar >= M) ar = M - 1;
      async16(A + (size_t)ar * K + kt + lc, &Asb[tr * 32]);
      int br = bn + tr + lr;
      async16(BT + (size_t)br * K + kt + lc, &Bsb[tr * 32]);
    }
    __syncthreads();

    bf16x8 af[4], bfr[4];
#pragma unroll
    for (int m = 0; m < 4; m++)
      af[m] = *reinterpret_cast<const bf16x8*>(
          &Asb[(wr * 64 + m * 16 + (l & 15)) * 32 + (l >> 4) * 8]);
#pragma unroll
    for (int n = 0; n < 4; n++)
      bfr[n] = *reinterpret_cast<const bf16x8*>(
          &Bsb[(wc * 64 + n * 16 + (l & 15)) * 32 + (l >> 4) * 8]);
#pragma unroll
    for (int m = 0; m < 4; m++)
#pragma unroll
      for (int n = 0; n < 4; n++)
        acc[m][n] = __builtin_amdgcn_mfma_f32_16x16x32_bf16(
            af[m], bfr[n], acc[m][n], 0, 0, 0);
  }

#pragma unroll
  for (int m = 0; m < 4; m++) {
    int row0 = bm + wr * 64 + m * 16 + ((l >> 4) << 2);
#pragma unroll
    for (int n = 0; n < 4; n++) {
      int col = bn + wc * 64 + n * 16 + (l & 15);
      float bv = bias[col];
#pragma unroll
      for (int r = 0; r < 4; r++) {
        int row = row0 + r;
        if (row < M) {
          float v = acc[m][n][r] + bv;
          if (RELU) v = fmaxf(v, 0.0f);
          if (MODE == 0) Cb[(size_t)row * N + col] = f2bf(v);
          if (MODE == 2) Cf[(size_t)row * N + col] = v;
          if (MODE == 3)
            Cb[((size_t)(col >> 5) * NN + row) * 32 + (col & 31)] = f2bf(v);
        }
      }
    }
  }
}

// ---------------------------------------------------------------------------
// workspace layout (bytes); overlapped lifetimes:
//  xbS  [ 0.0 .. 12.8M)  bf16 [4][NN][32]  (cvt_sl -> gather1)
//  z1b  [12.8 .. 25.6M)  bf16 [NN][128]    (gather1 -> gemm1)
//  h1b  [25.6 .. 51.2M)  bf16 [NN][256]    (gemm1 -> gemm2)
//  hbS  [51.2 .. 76.8M)  bf16 [8][NN][32]  (gemm2 -> gather2)
//  z2b  [ 0.0 .. 25.6M)  bf16 [NN][256]    (gather2 -> gemm3)  over xbS+z1b
//  h2b  [25.6 .. 51.2M)  bf16 [NN][256]    (gemm3 -> gemm4)    over h1b
//  CSR  [76.8M ..)       offs[50001], cursor/counts[50000], srcs[800000], bsum
//  WT   [80.4M ..)       bf16 weights
static const size_t OFF_XBS  = 0;
static const size_t OFF_Z1B  = 12800000;
static const size_t OFF_H1B  = 25600000;
static const size_t OFF_HBS  = 51200000;
static const size_t OFF_Z2B  = 0;
static const size_t OFF_H2B  = 25600000;
static const size_t OFF_OFFS = 76800000;
static const size_t OFF_CNT  = 77000064;
static const size_t OFF_SRC  = 77200128;
static const size_t OFF_BSUM = 80400128;
static const size_t OFF_WT   = 80400512;

extern "C" void kernel_launch(void* const* d_in, const int* in_sizes, int n_in,
                              void* d_out, int out_size, void* d_ws, size_t ws_size,
                              hipStream_t stream)
{
  const float* x    = (const float*)d_in[0];
  const int*   ei   = (const int*)d_in[1];
  const float* W1a  = (const float*)d_in[2];
  const float* b1a  = (const float*)d_in[3];
  const float* W1b  = (const float*)d_in[4];
  const float* b1b  = (const float*)d_in[5];
  const float* eps1 = (const float*)d_in[6];
  const float* W2   = (const float*)d_in[7];
  const float* b2   = (const float*)d_in[8];
  const float* W3   = (const float*)d_in[9];
  const float* b3   = (const float*)d_in[10];

  char* ws = (char*)d_ws;
  unsigned short* xbS  = (unsigned short*)(ws + OFF_XBS);
  unsigned short* z1b  = (unsigned short*)(ws + OFF_Z1B);
  unsigned short* h1b  = (unsigned short*)(ws + OFF_H1B);
  unsigned short* hbS  = (unsigned short*)(ws + OFF_HBS);
  unsigned short* z2b  = (unsigned short*)(ws + OFF_Z2B);
  unsigned short* h2b  = (unsigned short*)(ws + OFF_H2B);
  int*            offs = (int*)(ws + OFF_OFFS);
  int*            cnts = (int*)(ws + OFF_CNT);
  int*            srcs = (int*)(ws + OFF_SRC);
  int*            bsum = (int*)(ws + OFF_BSUM);
  unsigned short* wt   = (unsigned short*)(ws + OFF_WT);
  unsigned short* w1at = wt;                 // [256][128]
  unsigned short* w1bt = wt + 32768;         // [256][256]
  unsigned short* w2t  = wt + 98304;         // [256][256]
  unsigned short* w3t  = wt + 163840;        // [128][256]

  // weights (one launch)
  k_wcvt_all<<<768, 256, 0, stream>>>(W1a, W1b, W2, W3, wt);

  // CSR build
  hipMemsetAsync(cnts, 0, 50000 * sizeof(int), stream);
  k_hist<<<(NE + 255) / 256, 256, 0, stream>>>(ei, cnts);
  k_scan_a<<<SCAN_NB, 1024, 0, stream>>>(cnts, offs, bsum);
  k_scan_b<<<SCAN_NB, 1024, 0, stream>>>(bsum, offs, cnts);
  k_scatter<<<(NE + 255) / 256, 256, 0, stream>>>(ei, cnts, srcs);

  // x -> bf16 slice-major
  k_cvt_sl<<<(NN * 64 + 255) / 256, 256, 0, stream>>>(x, xbS);

  // layer 1
  k_gather_sl<128, 4, true><<<NB16 * 4, 256, 0, stream>>>(
      offs, srcs, xbS, x, eps1, z1b);
  dim3 g1(391, 2);
  k_gemm<true, 0><<<g1, 256, 0, stream>>>(z1b, w1at, b1a, h1b, nullptr, NN, 128, 256);
  k_gemm<true, 3><<<g1, 256, 0, stream>>>(h1b, w1bt, b1b, hbS, nullptr, NN, 256, 256);

  // layer 2
  k_gather_sl<256, 8, false><<<NB16 * 8, 256, 0, stream>>>(
      offs, srcs, hbS, nullptr, nullptr, z2b);
  k_gemm<true, 0><<<g1, 256, 0, stream>>>(z2b, w2t, b2, h2b, nullptr, NN, 256, 256);
  dim3 g4(391, 1);
  k_gemm<false, 2><<<g4, 256, 0, stream>>>(h2b, w3t, b3, nullptr, (float*)d_out, NN, 256, 128);
}

// Round 6
// 277.504 us; speedup vs baseline: 1.3549x; 1.3549x over previous
//
#include <hip/hip_runtime.h>

// ---------------------------------------------------------------------------
// GIN forward. R5b: same as R5 (row-major gather with 16B/lane bf16x8 loads,
// BN=256 full-N GEMM tiles) with the compile fix: __builtin_nontemporal_load
// needs clang ext-vector types, not HIP_vector_type float4.
// ---------------------------------------------------------------------------

typedef __attribute__((ext_vector_type(8))) short bf16x8;
typedef __attribute__((ext_vector_type(4))) float f32x4;

__device__ __forceinline__ float bf2f(unsigned short u) {
  unsigned v = ((unsigned)u) << 16;
  return __builtin_bit_cast(float, v);
}
__device__ __forceinline__ unsigned short f2bf(float f) {
  unsigned u = __builtin_bit_cast(unsigned, f);
  u += 0x7fffu + ((u >> 16) & 1u);
  return (unsigned short)(u >> 16);
}

__device__ __forceinline__ void async16(const void* g, void* l) {
  __builtin_amdgcn_global_load_lds(
      (const __attribute__((address_space(1))) void*)g,
      (__attribute__((address_space(3))) void*)l, 16, 0, 0);
}

static const int NN = 50000;
static const int NE = 800000;
static const int SCAN_NB = 49;             // ceil(50000/1024)

// --- fp32 -> bf16 cast -----------------------------------------------------
__global__ __launch_bounds__(256) void k_cvt(const float* __restrict__ in,
    unsigned short* __restrict__ out, int n4)
{
  int i = blockIdx.x * 256 + threadIdx.x;
  if (i >= n4) return;
  float4 v = reinterpret_cast<const float4*>(in)[i];
  ushort4 b; b.x = f2bf(v.x); b.y = f2bf(v.y); b.z = f2bf(v.z); b.w = f2bf(v.w);
  reinterpret_cast<ushort4*>(out)[i] = b;
}

// --- all four weights: W [K][N] fp32 -> WT [N][K] bf16, one launch ---------
__global__ __launch_bounds__(256) void k_wcvt_all(
    const float* __restrict__ W1a, const float* __restrict__ W1b,
    const float* __restrict__ W2,  const float* __restrict__ W3,
    unsigned short* __restrict__ WT)
{
  int idx = blockIdx.x * 256 + threadIdx.x;   // 0 .. 196607
  const float* W; unsigned short* out; int K, N, li;
  if (idx < 32768)        { W = W1a; out = WT;          K = 128; N = 256; li = idx; }
  else if (idx < 98304)   { W = W1b; out = WT + 32768;  K = 256; N = 256; li = idx - 32768; }
  else if (idx < 163840)  { W = W2;  out = WT + 98304;  K = 256; N = 256; li = idx - 98304; }
  else if (idx < 196608)  { W = W3;  out = WT + 163840; K = 256; N = 128; li = idx - 163840; }
  else return;
  int n = li / K, k = li - n * K;
  out[li] = f2bf(W[k * N + n]);
}

// --- CSR build: histogram over dst ----------------------------------------
__global__ __launch_bounds__(256) void k_hist(const int* __restrict__ ei,
    int* __restrict__ counts)
{
  int e = blockIdx.x * 256 + threadIdx.x;
  if (e >= NE) return;
  atomicAdd(&counts[ei[NE + e]], 1);
}

// --- scan phase A: per-block inclusive scan (Hillis-Steele in LDS) ---------
__global__ __launch_bounds__(1024) void k_scan_a(const int* __restrict__ counts,
    int* __restrict__ offs, int* __restrict__ bsum)
{
  __shared__ int sh[1024];
  const int t = threadIdx.x;
  int idx = blockIdx.x * 1024 + t;
  int c = (idx < NN) ? counts[idx] : 0;
  sh[t] = c;
  __syncthreads();
  int v = c;
  for (int off = 1; off < 1024; off <<= 1) {
    int tmp = (t >= off) ? sh[t - off] : 0;
    __syncthreads();
    v += tmp; sh[t] = v;
    __syncthreads();
  }
  if (idx < NN) offs[idx] = v - c;
  if (t == 1023) bsum[blockIdx.x] = v;
}

// --- scan phase B: add block bases; copy to cursor; offs[NN]=NE ------------
__global__ __launch_bounds__(1024) void k_scan_b(const int* __restrict__ bsum,
    int* __restrict__ offs, int* __restrict__ cursor)
{
  __shared__ int sb[64];
  const int t = threadIdx.x;
  if (t < SCAN_NB) sb[t] = bsum[t];
  __syncthreads();
  int base = 0;
  for (int j = 0; j < SCAN_NB; j++) base += (j < (int)blockIdx.x) ? sb[j] : 0;
  int idx = blockIdx.x * 1024 + t;
  if (idx < NN) { int o = offs[idx] + base; offs[idx] = o; cursor[idx] = o; }
  if (blockIdx.x == 0 && t == 0) offs[NN] = NE;
}

// --- scatter src ids into CSR order ---------------------------------------
__global__ __launch_bounds__(256) void k_scatter(const int* __restrict__ ei,
    int* __restrict__ cursor, int* __restrict__ srcs)
{
  int e = blockIdx.x * 256 + threadIdx.x;
  if (e >= NE) return;
  int dst = ei[NE + e];
  int pos = atomicAdd(&cursor[dst], 1);
  srcs[pos] = ei[e];
}

// --- gather-aggregate v2: 16B/lane, C/8 lanes per node ---------------------
// out[n] = bf16(self(n) + sum_{s in N(n)} feat[s]);  feat row-major [NN][C].
// L1: self = (1+eps) * x_fp32[node]; else self = feat own row.
template<int C, bool L1>
__global__ __launch_bounds__(256) void k_gather(const int* __restrict__ offs,
    const int* __restrict__ srcs, const unsigned short* __restrict__ feat,
    const float* __restrict__ selfx, const float* __restrict__ eps,
    unsigned short* __restrict__ out)
{
  constexpr int TPN = C / 8;              // lanes per node (32 or 16)
  int tid = blockIdx.x * 256 + threadIdx.x;
  int node = tid / TPN;
  if (node >= NN) return;
  int c0 = (tid % TPN) * 8;               // element offset, 16B aligned

  float a[8];
  if (L1) {
    float sc = 1.0f + eps[0];
    const float* sp = selfx + (size_t)node * C + c0;
    f32x4 v0 = __builtin_nontemporal_load(reinterpret_cast<const f32x4*>(sp));
    f32x4 v1 = __builtin_nontemporal_load(reinterpret_cast<const f32x4*>(sp + 4));
    a[0] = v0.x * sc; a[1] = v0.y * sc; a[2] = v0.z * sc; a[3] = v0.w * sc;
    a[4] = v1.x * sc; a[5] = v1.y * sc; a[6] = v1.z * sc; a[7] = v1.w * sc;
  } else {
    bf16x8 v = *reinterpret_cast<const bf16x8*>(feat + (size_t)node * C + c0);
#pragma unroll
    for (int j = 0; j < 8; j++) a[j] = bf2f((unsigned short)v[j]);
  }

  int beg = __builtin_nontemporal_load(offs + node);
  int end = __builtin_nontemporal_load(offs + node + 1);
  int i = beg;
  for (; i + 2 <= end; i += 2) {
    int s0 = __builtin_nontemporal_load(srcs + i);
    int s1 = __builtin_nontemporal_load(srcs + i + 1);
    bf16x8 v0 = *reinterpret_cast<const bf16x8*>(feat + (size_t)s0 * C + c0);
    bf16x8 v1 = *reinterpret_cast<const bf16x8*>(feat + (size_t)s1 * C + c0);
#pragma unroll
    for (int j = 0; j < 8; j++) a[j] += bf2f((unsigned short)v0[j]);
#pragma unroll
    for (int j = 0; j < 8; j++) a[j] += bf2f((unsigned short)v1[j]);
  }
  if (i < end) {
    int s0 = __builtin_nontemporal_load(srcs + i);
    bf16x8 v0 = *reinterpret_cast<const bf16x8*>(feat + (size_t)s0 * C + c0);
#pragma unroll
    for (int j = 0; j < 8; j++) a[j] += bf2f((unsigned short)v0[j]);
  }

  bf16x8 o;
#pragma unroll
  for (int j = 0; j < 8; j++) o[j] = (short)f2bf(a[j]);
  __builtin_nontemporal_store(o,
      reinterpret_cast<bf16x8*>(out + (size_t)node * C + c0));
}

// --- bf16 MFMA GEMM: C = A[M][K] * BT[N][K]^T + bias, optional relu --------
// Tile 128 x BN_, BN_/32 waves (each wave 64x64), BK=32.
// MODE 0: bf16 row-major out; 2: fp32 row-major out
template<bool RELU, int MODE, int BN_>
__global__ __launch_bounds__(BN_ * 2) void k_gemm(
    const unsigned short* __restrict__ A,
    const unsigned short* __restrict__ BT,
    const float* __restrict__ bias,
    unsigned short* __restrict__ Cb,
    float* __restrict__ Cf,
    int M, int K, int N)
{
  constexpr int WC = BN_ / 64;            // waves per col-band (2 or 4)
  constexpr int NW = 2 * WC;              // total waves (4 or 8)
  __shared__ unsigned short Asb[128 * 32];
  __shared__ unsigned short Bsb[BN_ * 32];
  const int tid = threadIdx.x;
  const int w = tid >> 6, l = tid & 63;
  const int bm = blockIdx.x * 128, bn = blockIdx.y * BN_;
  const int wr = w / WC, wc = w % WC;

  f32x4 acc[4][4];
#pragma unroll
  for (int m = 0; m < 4; m++)
#pragma unroll
    for (int n = 0; n < 4; n++) acc[m][n] = (f32x4)(0.0f);

  const int lr = l >> 2;                  // row within 16-row chunk
  const int lc = (l & 3) * 8;             // bf16 col offset within BK=32

  for (int kt = 0; kt < K; kt += 32) {
    __syncthreads();
#pragma unroll
    for (int ch = w; ch < 8; ch += NW) {          // A: 128 rows = 8 chunks
      int tr = ch * 16;
      int ar = bm + tr + lr; if (ar >= M) ar = M - 1;
      async16(A + (size_t)ar * K + kt + lc, &Asb[tr * 32]);
    }
#pragma unroll
    for (int ch = w; ch < BN_ / 16; ch += NW) {   // B: BN_ rows
      int tr = ch * 16;
      int br = bn + tr + lr;                      // N % BN_ == 0
      async16(BT + (size_t)br * K + kt + lc, &Bsb[tr * 32]);
    }
    __syncthreads();

    bf16x8 af[4], bfr[4];
#pragma unroll
    for (int m = 0; m < 4; m++)
      af[m] = *reinterpret_cast<const bf16x8*>(
          &Asb[(wr * 64 + m * 16 + (l & 15)) * 32 + (l >> 4) * 8]);
#pragma unroll
    for (int n = 0; n < 4; n++)
      bfr[n] = *reinterpret_cast<const bf16x8*>(
          &Bsb[(wc * 64 + n * 16 + (l & 15)) * 32 + (l >> 4) * 8]);
#pragma unroll
    for (int m = 0; m < 4; m++)
#pragma unroll
      for (int n = 0; n < 4; n++)
        acc[m][n] = __builtin_amdgcn_mfma_f32_16x16x32_bf16(
            af[m], bfr[n], acc[m][n], 0, 0, 0);
  }

  // epilogue: C/D layout col = lane&15, row = (lane>>4)*4 + reg  [m89]
#pragma unroll
  for (int m = 0; m < 4; m++) {
    int row0 = bm + wr * 64 + m * 16 + ((l >> 4) << 2);
#pragma unroll
    for (int n = 0; n < 4; n++) {
      int col = bn + wc * 64 + n * 16 + (l & 15);
      float bv = bias[col];
#pragma unroll
      for (int r = 0; r < 4; r++) {
        int row = row0 + r;
        if (row < M) {
          float v = acc[m][n][r] + bv;
          if (RELU) v = fmaxf(v, 0.0f);
          if (MODE == 0) Cb[(size_t)row * N + col] = f2bf(v);
          if (MODE == 2) Cf[(size_t)row * N + col] = v;
        }
      }
    }
  }
}

// ---------------------------------------------------------------------------
// workspace layout (bytes); overlapped lifetimes:
//  xb   [ 0.0 .. 12.8M)  bf16 x        (cvt -> gather1)
//  z1b  [12.8 .. 25.6M)  bf16 z1       (gather1 -> gemm1)
//  h1b  [25.6 .. 51.2M)  bf16 h1       (gemm1 -> gemm2)
//  hb   [51.2 .. 76.8M)  bf16 h        (gemm2 -> gather2)
//  z2b  [ 0.0 .. 25.6M)  bf16 z2       (gather2 -> gemm3)   over xb+z1b (dead)
//  h2b  [25.6 .. 51.2M)  bf16 h2       (gemm3 -> gemm4)     over h1b (dead)
//  CSR  [76.8M ..)       offs[50001], cursor/counts[50000], srcs[800000], bsum
//  WT   [80.4M ..)       bf16 weights
static const size_t OFF_XB   = 0;
static const size_t OFF_Z1B  = 12800000;
static const size_t OFF_H1B  = 25600000;
static const size_t OFF_HB   = 51200000;
static const size_t OFF_Z2B  = 0;
static const size_t OFF_H2B  = 25600000;
static const size_t OFF_OFFS = 76800000;
static const size_t OFF_CNT  = 77000064;
static const size_t OFF_SRC  = 77200128;
static const size_t OFF_BSUM = 80400128;
static const size_t OFF_WT   = 80400512;

extern "C" void kernel_launch(void* const* d_in, const int* in_sizes, int n_in,
                              void* d_out, int out_size, void* d_ws, size_t ws_size,
                              hipStream_t stream)
{
  const float* x    = (const float*)d_in[0];
  const int*   ei   = (const int*)d_in[1];
  const float* W1a  = (const float*)d_in[2];
  const float* b1a  = (const float*)d_in[3];
  const float* W1b  = (const float*)d_in[4];
  const float* b1b  = (const float*)d_in[5];
  const float* eps1 = (const float*)d_in[6];
  const float* W2   = (const float*)d_in[7];
  const float* b2   = (const float*)d_in[8];
  const float* W3   = (const float*)d_in[9];
  const float* b3   = (const float*)d_in[10];

  char* ws = (char*)d_ws;
  unsigned short* xb   = (unsigned short*)(ws + OFF_XB);
  unsigned short* z1b  = (unsigned short*)(ws + OFF_Z1B);
  unsigned short* h1b  = (unsigned short*)(ws + OFF_H1B);
  unsigned short* hb   = (unsigned short*)(ws + OFF_HB);
  unsigned short* z2b  = (unsigned short*)(ws + OFF_Z2B);
  unsigned short* h2b  = (unsigned short*)(ws + OFF_H2B);
  int*            offs = (int*)(ws + OFF_OFFS);
  int*            cnts = (int*)(ws + OFF_CNT);
  int*            srcs = (int*)(ws + OFF_SRC);
  int*            bsum = (int*)(ws + OFF_BSUM);
  unsigned short* wt   = (unsigned short*)(ws + OFF_WT);
  unsigned short* w1at = wt;                 // [256][128]
  unsigned short* w1bt = wt + 32768;         // [256][256]
  unsigned short* w2t  = wt + 98304;         // [256][256]
  unsigned short* w3t  = wt + 163840;        // [128][256]

  // weights (one launch)
  k_wcvt_all<<<768, 256, 0, stream>>>(W1a, W1b, W2, W3, wt);

  // CSR build
  hipMemsetAsync(cnts, 0, 50000 * sizeof(int), stream);
  k_hist<<<(NE + 255) / 256, 256, 0, stream>>>(ei, cnts);
  k_scan_a<<<SCAN_NB, 1024, 0, stream>>>(cnts, offs, bsum);
  k_scan_b<<<SCAN_NB, 1024, 0, stream>>>(bsum, offs, cnts);
  k_scatter<<<(NE + 255) / 256, 256, 0, stream>>>(ei, cnts, srcs);

  // x -> bf16
  k_cvt<<<(NN * 128 / 4 + 255) / 256, 256, 0, stream>>>(x, xb, NN * 128 / 4);

  // layer 1  (gather: 16 lanes/node for C=128 -> 800000 threads)
  k_gather<128, true><<<NN * 16 / 256, 256, 0, stream>>>(
      offs, srcs, xb, x, eps1, z1b);
  dim3 g1(391, 1);
  k_gemm<true, 0, 256><<<g1, 512, 0, stream>>>(z1b, w1at, b1a, h1b, nullptr, NN, 128, 256);
  k_gemm<true, 0, 256><<<g1, 512, 0, stream>>>(h1b, w1bt, b1b, hb, nullptr, NN, 256, 256);

  // layer 2  (gather: 32 lanes/node for C=256 -> 1600000 threads)
  k_gather<256, false><<<NN * 32 / 256, 256, 0, stream>>>(
      offs, srcs, hb, nullptr, nullptr, z2b);
  k_gemm<true, 0, 256><<<g1, 512, 0, stream>>>(z2b, w2t, b2, h2b, nullptr, NN, 256, 256);
  k_gemm<false, 2, 128><<<g1, 256, 0, stream>>>(h2b, w3t, b3, nullptr, (float*)d_out, NN, 256, 128);
}

// Round 7
// 265.175 us; speedup vs baseline: 1.4179x; 1.0465x over previous
//
#include <hip/hip_runtime.h>

// ---------------------------------------------------------------------------
// GIN forward. R7: (1) gather neighbor loop unrolled 4x (test latency- vs
// BW-bound: R3 8B/lane and R6 16B/lane both 64us at same FETCH_SIZE);
// (2) GEMM double-buffered 2-phase pipeline (stage next K-tile during MFMA,
// one barrier per K-step); (3) wcvt+cvt+hist fused into one k_prep launch.
// ---------------------------------------------------------------------------

typedef __attribute__((ext_vector_type(8))) short bf16x8;
typedef __attribute__((ext_vector_type(4))) float f32x4;

__device__ __forceinline__ float bf2f(unsigned short u) {
  unsigned v = ((unsigned)u) << 16;
  return __builtin_bit_cast(float, v);
}
__device__ __forceinline__ unsigned short f2bf(float f) {
  unsigned u = __builtin_bit_cast(unsigned, f);
  u += 0x7fffu + ((u >> 16) & 1u);
  return (unsigned short)(u >> 16);
}

__device__ __forceinline__ void async16(const void* g, void* l) {
  __builtin_amdgcn_global_load_lds(
      (const __attribute__((address_space(1))) void*)g,
      (__attribute__((address_space(3))) void*)l, 16, 0, 0);
}

static const int NN = 50000;
static const int NE = 800000;
static const int SCAN_NB = 49;             // ceil(50000/1024)

// --- fused prep: weight transpose+cast | x cast | dst histogram ------------
// ranges: [0,196608) weights; [196608,196608+1.6M) x-cvt; rest: hist
__global__ __launch_bounds__(256) void k_prep(
    const float* __restrict__ W1a, const float* __restrict__ W1b,
    const float* __restrict__ W2,  const float* __restrict__ W3,
    unsigned short* __restrict__ WT,
    const float* __restrict__ x, unsigned short* __restrict__ xb,
    const int* __restrict__ ei, int* __restrict__ counts)
{
  int idx = blockIdx.x * 256 + threadIdx.x;
  if (idx < 196608) {
    const float* W; unsigned short* out; int K, N, li;
    if (idx < 32768)       { W = W1a; out = WT;          K = 128; N = 256; li = idx; }
    else if (idx < 98304)  { W = W1b; out = WT + 32768;  K = 256; N = 256; li = idx - 32768; }
    else if (idx < 163840) { W = W2;  out = WT + 98304;  K = 256; N = 256; li = idx - 98304; }
    else                   { W = W3;  out = WT + 163840; K = 256; N = 128; li = idx - 163840; }
    int n = li / K, k = li - n * K;
    out[li] = f2bf(W[k * N + n]);
  } else if (idx < 196608 + NN * 32) {     // NN*128/4 = 1.6M float4 units
    int i = idx - 196608;
    float4 v = reinterpret_cast<const float4*>(x)[i];
    ushort4 b; b.x = f2bf(v.x); b.y = f2bf(v.y); b.z = f2bf(v.z); b.w = f2bf(v.w);
    reinterpret_cast<ushort4*>(xb)[i] = b;
  } else {
    int e = idx - 196608 - NN * 32;
    if (e < NE) atomicAdd(&counts[ei[NE + e]], 1);
  }
}

// --- scan phase A: per-block inclusive scan (Hillis-Steele in LDS) ---------
__global__ __launch_bounds__(1024) void k_scan_a(const int* __restrict__ counts,
    int* __restrict__ offs, int* __restrict__ bsum)
{
  __shared__ int sh[1024];
  const int t = threadIdx.x;
  int idx = blockIdx.x * 1024 + t;
  int c = (idx < NN) ? counts[idx] : 0;
  sh[t] = c;
  __syncthreads();
  int v = c;
  for (int off = 1; off < 1024; off <<= 1) {
    int tmp = (t >= off) ? sh[t - off] : 0;
    __syncthreads();
    v += tmp; sh[t] = v;
    __syncthreads();
  }
  if (idx < NN) offs[idx] = v - c;
  if (t == 1023) bsum[blockIdx.x] = v;
}

// --- scan phase B: add block bases; copy to cursor; offs[NN]=NE ------------
__global__ __launch_bounds__(1024) void k_scan_b(const int* __restrict__ bsum,
    int* __restrict__ offs, int* __restrict__ cursor)
{
  __shared__ int sb[64];
  const int t = threadIdx.x;
  if (t < SCAN_NB) sb[t] = bsum[t];
  __syncthreads();
  int base = 0;
  for (int j = 0; j < SCAN_NB; j++) base += (j < (int)blockIdx.x) ? sb[j] : 0;
  int idx = blockIdx.x * 1024 + t;
  if (idx < NN) { int o = offs[idx] + base; offs[idx] = o; cursor[idx] = o; }
  if (blockIdx.x == 0 && t == 0) offs[NN] = NE;
}

// --- scatter src ids into CSR order ---------------------------------------
__global__ __launch_bounds__(256) void k_scatter(const int* __restrict__ ei,
    int* __restrict__ cursor, int* __restrict__ srcs)
{
  int e = blockIdx.x * 256 + threadIdx.x;
  if (e >= NE) return;
  int dst = ei[NE + e];
  int pos = atomicAdd(&cursor[dst], 1);
  srcs[pos] = ei[e];
}

// --- gather-aggregate v3: 16B/lane, 4-deep unroll --------------------------
// out[n] = bf16(self(n) + sum_{s in N(n)} feat[s]);  feat row-major [NN][C].
// L1: self = (1+eps) * x_fp32[node]; else self = feat own row.
template<int C, bool L1>
__global__ __launch_bounds__(256) void k_gather(const int* __restrict__ offs,
    const int* __restrict__ srcs, const unsigned short* __restrict__ feat,
    const float* __restrict__ selfx, const float* __restrict__ eps,
    unsigned short* __restrict__ out)
{
  constexpr int TPN = C / 8;              // lanes per node (32 or 16)
  int tid = blockIdx.x * 256 + threadIdx.x;
  int node = tid / TPN;
  if (node >= NN) return;
  int c0 = (tid % TPN) * 8;               // element offset, 16B aligned

  float a[8];
  if (L1) {
    float sc = 1.0f + eps[0];
    const float* sp = selfx + (size_t)node * C + c0;
    f32x4 v0 = __builtin_nontemporal_load(reinterpret_cast<const f32x4*>(sp));
    f32x4 v1 = __builtin_nontemporal_load(reinterpret_cast<const f32x4*>(sp + 4));
    a[0] = v0.x * sc; a[1] = v0.y * sc; a[2] = v0.z * sc; a[3] = v0.w * sc;
    a[4] = v1.x * sc; a[5] = v1.y * sc; a[6] = v1.z * sc; a[7] = v1.w * sc;
  } else {
    bf16x8 v = *reinterpret_cast<const bf16x8*>(feat + (size_t)node * C + c0);
#pragma unroll
    for (int j = 0; j < 8; j++) a[j] = bf2f((unsigned short)v[j]);
  }

  int beg = __builtin_nontemporal_load(offs + node);
  int end = __builtin_nontemporal_load(offs + node + 1);
  int i = beg;
  for (; i + 4 <= end; i += 4) {
    int s0 = __builtin_nontemporal_load(srcs + i);
    int s1 = __builtin_nontemporal_load(srcs + i + 1);
    int s2 = __builtin_nontemporal_load(srcs + i + 2);
    int s3 = __builtin_nontemporal_load(srcs + i + 3);
    bf16x8 v0 = *reinterpret_cast<const bf16x8*>(feat + (size_t)s0 * C + c0);
    bf16x8 v1 = *reinterpret_cast<const bf16x8*>(feat + (size_t)s1 * C + c0);
    bf16x8 v2 = *reinterpret_cast<const bf16x8*>(feat + (size_t)s2 * C + c0);
    bf16x8 v3 = *reinterpret_cast<const bf16x8*>(feat + (size_t)s3 * C + c0);
#pragma unroll
    for (int j = 0; j < 8; j++) a[j] += bf2f((unsigned short)v0[j]);
#pragma unroll
    for (int j = 0; j < 8; j++) a[j] += bf2f((unsigned short)v1[j]);
#pragma unroll
    for (int j = 0; j < 8; j++) a[j] += bf2f((unsigned short)v2[j]);
#pragma unroll
    for (int j = 0; j < 8; j++) a[j] += bf2f((unsigned short)v3[j]);
  }
  for (; i < end; ++i) {
    int s0 = __builtin_nontemporal_load(srcs + i);
    bf16x8 v0 = *reinterpret_cast<const bf16x8*>(feat + (size_t)s0 * C + c0);
#pragma unroll
    for (int j = 0; j < 8; j++) a[j] += bf2f((unsigned short)v0[j]);
  }

  bf16x8 o;
#pragma unroll
  for (int j = 0; j < 8; j++) o[j] = (short)f2bf(a[j]);
  __builtin_nontemporal_store(o,
      reinterpret_cast<bf16x8*>(out + (size_t)node * C + c0));
}

// --- bf16 MFMA GEMM, double-buffered 2-phase pipeline ----------------------
// C = A[M][K] * BT[N][K]^T + bias, optional relu.
// Tile 128 x BN_, BN_/32 waves of 64x64 each, BK=32, 2 LDS buffers:
// stage(next) issued before ds_read/MFMA(cur); one __syncthreads per K-step
// (drains vmcnt for the stage + lgkm, barriers). MODE 0: bf16 out; 2: fp32.
template<bool RELU, int MODE, int BN_>
__global__ __launch_bounds__(BN_ * 2) void k_gemm(
    const unsigned short* __restrict__ A,
    const unsigned short* __restrict__ BT,
    const float* __restrict__ bias,
    unsigned short* __restrict__ Cb,
    float* __restrict__ Cf,
    int M, int K, int N)
{
  constexpr int WC = BN_ / 64;            // waves per col-band (2 or 4)
  constexpr int NW = 2 * WC;              // total waves (4 or 8)
  __shared__ unsigned short Asb[2][128 * 32];
  __shared__ unsigned short Bsb[2][BN_ * 32];
  const int tid = threadIdx.x;
  const int w = tid >> 6, l = tid & 63;
  const int bm = blockIdx.x * 128, bn = blockIdx.y * BN_;
  const int wr = w / WC, wc = w % WC;

  f32x4 acc[4][4];
#pragma unroll
  for (int m = 0; m < 4; m++)
#pragma unroll
    for (int n = 0; n < 4; n++) acc[m][n] = (f32x4)(0.0f);

  const int lr = l >> 2;                  // row within 16-row chunk
  const int lc = (l & 3) * 8;             // bf16 col offset within BK=32

  auto stage = [&](int buf, int kt) {
#pragma unroll
    for (int ch = w; ch < 8; ch += NW) {          // A: 128 rows = 8 chunks
      int tr = ch * 16;
      int ar = bm + tr + lr; if (ar >= M) ar = M - 1;
      async16(A + (size_t)ar * K + kt + lc, &Asb[buf][tr * 32]);
    }
#pragma unroll
    for (int ch = w; ch < BN_ / 16; ch += NW) {   // B: BN_ rows
      int tr = ch * 16;
      int br = bn + tr + lr;                      // N % BN_ == 0
      async16(BT + (size_t)br * K + kt + lc, &Bsb[buf][tr * 32]);
    }
  };

  stage(0, 0);
  __syncthreads();

  int cur = 0;
  for (int kt = 0; kt < K; kt += 32) {
    if (kt + 32 < K) stage(cur ^ 1, kt + 32);

    bf16x8 af[4], bfr[4];
#pragma unroll
    for (int m = 0; m < 4; m++)
      af[m] = *reinterpret_cast<const bf16x8*>(
          &Asb[cur][(wr * 64 + m * 16 + (l & 15)) * 32 + (l >> 4) * 8]);
#pragma unroll
    for (int n = 0; n < 4; n++)
      bfr[n] = *reinterpret_cast<const bf16x8*>(
          &Bsb[cur][(wc * 64 + n * 16 + (l & 15)) * 32 + (l >> 4) * 8]);
#pragma unroll
    for (int m = 0; m < 4; m++)
#pragma unroll
      for (int n = 0; n < 4; n++)
        acc[m][n] = __builtin_amdgcn_mfma_f32_16x16x32_bf16(
            af[m], bfr[n], acc[m][n], 0, 0, 0);

    __syncthreads();                      // drains stage vmcnt + barriers
    cur ^= 1;
  }

  // epilogue: C/D layout col = lane&15, row = (lane>>4)*4 + reg  [m89]
#pragma unroll
  for (int m = 0; m < 4; m++) {
    int row0 = bm + wr * 64 + m * 16 + ((l >> 4) << 2);
#pragma unroll
    for (int n = 0; n < 4; n++) {
      int col = bn + wc * 64 + n * 16 + (l & 15);
      float bv = bias[col];
#pragma unroll
      for (int r = 0; r < 4; r++) {
        int row = row0 + r;
        if (row < M) {
          float v = acc[m][n][r] + bv;
          if (RELU) v = fmaxf(v, 0.0f);
          if (MODE == 0) Cb[(size_t)row * N + col] = f2bf(v);
          if (MODE == 2) Cf[(size_t)row * N + col] = v;
        }
      }
    }
  }
}

// ---------------------------------------------------------------------------
// workspace layout (bytes); overlapped lifetimes:
//  xb   [ 0.0 .. 12.8M)  bf16 x        (prep -> gather1)
//  z1b  [12.8 .. 25.6M)  bf16 z1       (gather1 -> gemm1)
//  h1b  [25.6 .. 51.2M)  bf16 h1       (gemm1 -> gemm2)
//  hb   [51.2 .. 76.8M)  bf16 h        (gemm2 -> gather2)
//  z2b  [ 0.0 .. 25.6M)  bf16 z2       (gather2 -> gemm3)   over xb+z1b (dead)
//  h2b  [25.6 .. 51.2M)  bf16 h2       (gemm3 -> gemm4)     over h1b (dead)
//  CSR  [76.8M ..)       offs[50001], cursor/counts[50000], srcs[800000], bsum
//  WT   [80.4M ..)       bf16 weights
static const size_t OFF_XB   = 0;
static const size_t OFF_Z1B  = 12800000;
static const size_t OFF_H1B  = 25600000;
static const size_t OFF_HB   = 51200000;
static const size_t OFF_Z2B  = 0;
static const size_t OFF_H2B  = 25600000;
static const size_t OFF_OFFS = 76800000;
static const size_t OFF_CNT  = 77000064;
static const size_t OFF_SRC  = 77200128;
static const size_t OFF_BSUM = 80400128;
static const size_t OFF_WT   = 80400512;

extern "C" void kernel_launch(void* const* d_in, const int* in_sizes, int n_in,
                              void* d_out, int out_size, void* d_ws, size_t ws_size,
                              hipStream_t stream)
{
  const float* x    = (const float*)d_in[0];
  const int*   ei   = (const int*)d_in[1];
  const float* W1a  = (const float*)d_in[2];
  const float* b1a  = (const float*)d_in[3];
  const float* W1b  = (const float*)d_in[4];
  const float* b1b  = (const float*)d_in[5];
  const float* eps1 = (const float*)d_in[6];
  const float* W2   = (const float*)d_in[7];
  const float* b2   = (const float*)d_in[8];
  const float* W3   = (const float*)d_in[9];
  const float* b3   = (const float*)d_in[10];

  char* ws = (char*)d_ws;
  unsigned short* xb   = (unsigned short*)(ws + OFF_XB);
  unsigned short* z1b  = (unsigned short*)(ws + OFF_Z1B);
  unsigned short* h1b  = (unsigned short*)(ws + OFF_H1B);
  unsigned short* hb   = (unsigned short*)(ws + OFF_HB);
  unsigned short* z2b  = (unsigned short*)(ws + OFF_Z2B);
  unsigned short* h2b  = (unsigned short*)(ws + OFF_H2B);
  int*            offs = (int*)(ws + OFF_OFFS);
  int*            cnts = (int*)(ws + OFF_CNT);
  int*            srcs = (int*)(ws + OFF_SRC);
  int*            bsum = (int*)(ws + OFF_BSUM);
  unsigned short* wt   = (unsigned short*)(ws + OFF_WT);
  unsigned short* w1at = wt;                 // [256][128]
  unsigned short* w1bt = wt + 32768;         // [256][256]
  unsigned short* w2t  = wt + 98304;         // [256][256]
  unsigned short* w3t  = wt + 163840;        // [128][256]

  // prep: weights + x->bf16 + histogram (one launch; memset first)
  hipMemsetAsync(cnts, 0, 50000 * sizeof(int), stream);
  k_prep<<<(196608 + NN * 32 + NE) / 256, 256, 0, stream>>>(
      W1a, W1b, W2, W3, wt, x, xb, ei, cnts);

  // CSR finish
  k_scan_a<<<SCAN_NB, 1024, 0, stream>>>(cnts, offs, bsum);
  k_scan_b<<<SCAN_NB, 1024, 0, stream>>>(bsum, offs, cnts);
  k_scatter<<<(NE + 255) / 256, 256, 0, stream>>>(ei, cnts, srcs);

  // layer 1  (gather: 16 lanes/node for C=128 -> 800000 threads)
  k_gather<128, true><<<NN * 16 / 256, 256, 0, stream>>>(
      offs, srcs, xb, x, eps1, z1b);
  dim3 g1(391, 1);
  k_gemm<true, 0, 256><<<g1, 512, 0, stream>>>(z1b, w1at, b1a, h1b, nullptr, NN, 128, 256);
  k_gemm<true, 0, 256><<<g1, 512, 0, stream>>>(h1b, w1bt, b1b, hb, nullptr, NN, 256, 256);

  // layer 2  (gather: 32 lanes/node for C=256 -> 1600000 threads)
  k_gather<256, false><<<NN * 32 / 256, 256, 0, stream>>>(
      offs, srcs, hb, nullptr, nullptr, z2b);
  k_gemm<true, 0, 256><<<g1, 512, 0, stream>>>(z2b, w2t, b2, h2b, nullptr, NN, 256, 256);
  k_gemm<false, 2, 128><<<g1, 256, 0, stream>>>(h2b, w3t, b3, nullptr, (float*)d_out, NN, 256, 128);
}